// Round 27
// baseline (162.719 us; speedup 1.0000x reference)
//
#include <hip/hip_runtime.h>
#include <hip/hip_fp16.h>
#include <math.h>

#define TT 8192
#define FF 64
#define TILE 32
#define HALO 50
#define ROWS 82              // TILE + HALO
#define XSTR 72              // f16 row stride for xsH (144B, 16B-aligned)

typedef float f32x2 __attribute__((ext_vector_type(2)));
typedef float f32x4 __attribute__((ext_vector_type(4)));
typedef _Float16 f16x8 __attribute__((ext_vector_type(8)));
typedef unsigned int u32x4 __attribute__((ext_vector_type(4)));
typedef unsigned int u32x2 __attribute__((ext_vector_type(2)));

__device__ __forceinline__ float rcpf(float x) { return __builtin_amdgcn_rcpf(x); }

// ---- prep: wsmT[j*64+i] = f32 softmax(W)[i][j]; pwB = f16 MFMA B-frags of PW;
//      cpad[57]: cpad[q] = coeffs[q-3] for 0<=q-3<=50 else 0
__global__ void prep_kernel(const float* __restrict__ W, const float* __restrict__ PW,
                            const float* __restrict__ C,
                            float* __restrict__ wsmT, u32x4* __restrict__ pwB,
                            float* __restrict__ cpad) {
    const int lane = threadIdx.x;
    const int wv   = threadIdx.y;
    const int tid  = wv * 64 + lane;
    for (int it = 0; it < 16; ++it) {
        const int r = wv * 16 + it;
        float v = W[r * 64 + lane];
        float m = v;
        #pragma unroll
        for (int off = 32; off >= 1; off >>= 1)
            m = fmaxf(m, __shfl_xor(m, off, 64));
        float e = __expf(v - m);
        float s = e;
        #pragma unroll
        for (int off = 32; off >= 1; off >>= 1)
            s += __shfl_xor(s, off, 64);
        wsmT[lane * 64 + r] = e * rcpf(s);     // [j][i] f32
    }
    for (int s = tid; s < 512; s += 256) {
        const int n2 = s >> 6;
        const int ln = s & 63;
        const int i  = (n2 >> 1) * 16 + (ln & 15);
        const int k0 = (n2 & 1) * 32 + (ln >> 4) * 8;
        u32x4 frag;
        #pragma unroll
        for (int w = 0; w < 4; ++w) {
            const unsigned lo = __half_as_ushort(__float2half_rn(PW[i * 64 + k0 + 2 * w]));
            const unsigned hi = __half_as_ushort(__float2half_rn(PW[i * 64 + k0 + 2 * w + 1]));
            frag[w] = lo | (hi << 16);
        }
        pwB[s] = frag;
    }
    if (tid < 57) {
        const int k = tid - 3;
        cpad[tid] = (k >= 0 && k <= 50) ? C[k] : 0.f;
    }
}

// ---- fused main: 512 thr / 8 waves, 32-row tile; wave = 8 feats (uniform),
//      lane = (h = feat-half, r = row); w via wave-uniform s_load + cndmask ----
__global__ __launch_bounds__(512, 4)
void mcao_main(const float* __restrict__ x,
               const float* __restrict__ wsm,
               const u32x4* __restrict__ pwB,
               const float* __restrict__ cpad,
               const float* __restrict__ pb,
               const float* __restrict__ kap,
               float* __restrict__ out,
               float* __restrict__ memout) {
    // LDS 28704 B -> 5 blocks/CU capacity; grid 1024 = exactly 4/CU = 32 waves/CU:
    //   [0, 11808)      xsH f16 [82][72]   FIR stream + MFMA-A
    //   [11808, 20256)  tS  f32 [64][33]   tanh[feat][row]; P2 overlays after bar2
    //   [20256, 28704)  uS  f32 [64][33]   e^-|x|[feat][row]
    __shared__ __align__(16) char smem[28704];
    __half* xsH = (__half*)smem;
    float*  tS  = (float*)(smem + 11808);
    float*  P2  = (float*)(smem + 11808);
    float*  uS  = (float*)(smem + 20256);

    const int tid  = threadIdx.x;
    const int lane = tid & 63;
    const int wv   = tid >> 6;              // 0..7

    // XCD-aware bijective swizzle: 1024 blocks -> 128 consecutive tiles per XCD
    const int sw = ((int)blockIdx.x & 7) * 128 + ((int)blockIdx.x >> 3);
    const int b  = sw >> 8;                 // 0..3
    const int t0 = (sw & 255) * TILE;
    const float* xb = x + (size_t)b * TT * FF;

    // ---- stage xsH (f16): 82 rows from t0-50 ----
    for (int i4 = tid; i4 < ROWS * 16; i4 += 512) {
        const int s = i4 >> 4, f4 = i4 & 15, t = t0 - HALO + s;
        f32x4 v = {0.f, 0.f, 0.f, 0.f};
        if (t >= 0) v = *(const f32x4*)(xb + (size_t)t * 64 + f4 * 4);
        __half hv[4];
        #pragma unroll
        for (int q = 0; q < 4; ++q) hv[q] = __float2half_rn(v[q]);
        *(u32x2*)(&xsH[s * XSTR + f4 * 4]) = *(u32x2*)hv;
    }
    // ---- planes: thread -> (row = tid>>4, feats (tid&15)*4..+3), f32 source ----
    {
        const int row = tid >> 4, f0 = (tid & 15) * 4;
        const f32x4 v = *(const f32x4*)(xb + (size_t)(t0 + row) * 64 + f0);
        #pragma unroll
        for (int q = 0; q < 4; ++q) {
            tS[(f0 + q) * 33 + row] = fmaf(-2.f, rcpf(__expf(2.f * v[q]) + 1.f), 1.f);
            uS[(f0 + q) * 33 + row] = __expf(-fabsf(v[q]));
        }
    }
    __syncthreads();                                    // bar1

    // ---- proj via MFMA: wave -> C-tile (mt = wv>>2, nt = wv&3) ----
    const int mt = wv >> 2, nt = wv & 3;
    const int marow = HALO + mt * 16 + (lane & 15);
    const int kcol  = (lane >> 4) * 8;
    f32x4 cfr = {0.f, 0.f, 0.f, 0.f};
    #pragma unroll
    for (int kt = 0; kt < 2; ++kt) {
        const f16x8 afr = *(const f16x8*)(&xsH[marow * XSTR + kt * 32 + kcol]);
        const f16x8 bfr = __builtin_bit_cast(f16x8, pwB[(nt * 2 + kt) * 64 + lane]);
        cfr = __builtin_amdgcn_mfma_f32_16x16x32_f16(afr, bfr, cfr, 0, 0, 0);
    }

    // ---- megaloop setup: lane = (h, r); wave feats fb..fb+7 (uniform), lane's 4 = fb+4h ----
    const int r    = lane & 31;
    const int h    = lane >> 5;
    const int fb_u = __builtin_amdgcn_readfirstlane(wv * 8);   // uniform feat base
    const int ib   = fb_u + 4 * h;                             // lane's feat base
    const float* wbase = wsm + fb_u;
    f32x2 tiP[2], uiP[2];
    #pragma unroll
    for (int q = 0; q < 4; ++q) {
        tiP[q >> 1][q & 1] = tS[(ib + q) * 33 + r];
        uiP[q >> 1][q & 1] = uS[(ib + q) * 33 + r];
    }

    float macc[4] = {0.f, 0.f, 0.f, 0.f};
    f32x2 cac[2] = {{0.f, 0.f}, {0.f, 0.f}};
    const f32x2 one2 = {1.f, 1.f};
    const int firrow = 4 * wv;              // FIR rows 4wv..4wv+3 (lane = feature)

    // ---- megaloop m = 0..63: coupling all m (w s_load + cndmask); FIR m < 54 ----
    #pragma unroll
    for (int m = 0; m < 64; ++m) {
        const float tj = tS[m * 33 + r];                 // 32-addr 2-lane bcast: free
        const float uj = uS[m * 33 + r];
        const f32x4 wLo = *(const f32x4*)(wbase + m * 64);      // uniform s_load
        const f32x4 wHi = *(const f32x4*)(wbase + m * 64 + 4);  // uniform s_load
        const f32x4 wsel = h ? wHi : wLo;                // 4 v_cndmask
        if (m < 54) {
            const float xv = __half2float(xsH[(firrow + m) * XSTR + lane]);  // lane=feat
            #pragma unroll
            for (int r2 = 0; r2 < 4; ++r2)
                macc[r2] = fmaf(cpad[r2 + 53 - m], xv, macc[r2]);   // SGPR coeff
        }
        const f32x2 tjj = {tj, tj}, ujj = {uj, uj};
        #pragma unroll
        for (int g = 0; g < 2; ++g) {
            const f32x2 d1  = __builtin_elementwise_fma(-tiP[g], tjj, one2);
            const f32x2 d2  = __builtin_elementwise_fma( uiP[g], ujj, one2);
            const f32x2 den = d1 * d2;
            f32x2 rr; rr.x = rcpf(den.x); rr.y = rcpf(den.y);
            const f32x2 s = (tiP[g] - tjj) * rr;
            f32x2 wg; wg.x = wsel[2 * g]; wg.y = wsel[2 * g + 1];
            cac[g] = __builtin_elementwise_fma(wg, s, cac[g]);
        }
    }

    // ---- memory-term store (lane = feature, rows 4wv..4wv+3) ----
    #pragma unroll
    for (int r2 = 0; r2 < 4; ++r2)
        memout[(size_t)(b * TT + t0 + firrow + r2) * 64 + lane] = macc[r2];

    __syncthreads();                                    // bar2 (tS/uS reads done)

    // ---- proj C-frag -> P2 (overlays tS) ----
    {
        const int ic = nt * 16 + (lane & 15);
        const int rb = mt * 16 + (lane >> 4) * 4;
        #pragma unroll
        for (int reg = 0; reg < 4; ++reg)
            P2[ic * 33 + rb + reg] = cfr[reg];
    }
    __syncthreads();                                    // bar3

    // ---- epilogue RMW: P2 <- 0.4c + 0.3(proj+pb)ksum ----
    const float kappa = kap[0];
    const float ksum  = (1.f - __expf(-kappa * (float)(t0 + r + 1))) *
                        rcpf(1.f - __expf(-kappa));
    const f32x4 pbv = *(const f32x4*)(pb + ib);
    #pragma unroll
    for (int q = 0; q < 4; ++q) {
        const float cv  = (q & 1) ? cac[q >> 1].y : cac[q >> 1].x;
        const int   idx = (ib + q) * 33 + r;
        P2[idx] = fmaf(0.4f, cv, 0.3f * (P2[idx] + pbv[q]) * ksum);
    }
    __syncthreads();                                    // bar4

    // ---- add 0.3*macc (lane = feature, rows 4wv..4wv+3; (lane+row)%32 distinct) ----
    #pragma unroll
    for (int r2 = 0; r2 < 4; ++r2) {
        const int idx = lane * 33 + firrow + r2;
        P2[idx] = fmaf(0.3f, macc[r2], P2[idx]);
    }
    __syncthreads();                                    // bar5

    // ---- final store: thread -> (row = tid>>4, feats (tid&15)*4..+3), coalesced ----
    {
        const int row = tid >> 4, f0 = (tid & 15) * 4;
        f32x4 o;
        o.x = P2[(f0 + 0) * 33 + row];
        o.y = P2[(f0 + 1) * 33 + row];
        o.z = P2[(f0 + 2) * 33 + row];
        o.w = P2[(f0 + 3) * 33 + row];
        *(f32x4*)(out + (size_t)(b * TT + t0 + row) * 64 + f0) = o;
    }
}

extern "C" void kernel_launch(void* const* d_in, const int* in_sizes, int n_in,
                              void* d_out, int out_size, void* d_ws, size_t ws_size,
                              hipStream_t stream) {
    const float* x   = (const float*)d_in[0];
    const float* W   = (const float*)d_in[1];
    const float* PW  = (const float*)d_in[2];
    const float* pb  = (const float*)d_in[3];
    const float* kap = (const float*)d_in[4];
    const float* cf  = (const float*)d_in[5];

    float* out    = (float*)d_out;
    float* memout = out + (size_t)4 * TT * FF;

    float*  wsmT = (float*)d_ws;                        // 16 KB
    u32x4*  pwB  = (u32x4*)((char*)d_ws + 16384);       //  8 KB
    float*  cpad = (float*)((char*)d_ws + 24576);       // 228 B

    hipLaunchKernelGGL(prep_kernel, dim3(1), dim3(64, 4), 0, stream,
                       W, PW, cf, wsmT, pwB, cpad);
    hipLaunchKernelGGL(mcao_main, dim3(4 * (TT / TILE)), dim3(512), 0, stream,
                       x, wsmT, pwB, cpad, pb, kap, out, memout);
}

// Round 28
// 41.671 us; speedup vs baseline: 3.9049x; 3.9049x over previous
//
#include <hip/hip_runtime.h>
#include <hip/hip_fp16.h>
#include <math.h>

#define TT 8192
#define FF 64
#define TILE 64
#define HALO 50
#define ROWS 114             // TILE + HALO
#define XSTR 72              // f16 row stride for xsH

typedef float f32x2 __attribute__((ext_vector_type(2)));
typedef float f32x4 __attribute__((ext_vector_type(4)));
typedef _Float16 f16x8 __attribute__((ext_vector_type(8)));
typedef unsigned int u32x4 __attribute__((ext_vector_type(4)));
typedef unsigned int u32x2 __attribute__((ext_vector_type(2)));

__device__ __forceinline__ float rcpf(float x) { return __builtin_amdgcn_rcpf(x); }

// ---- prep: wsmT[j*64+i] = f32 softmax(W)[i][j]; pwB = f16 MFMA B-frags of PW;
//      cpad2[65]: cpad2[q] = coeffs[q-7] for 0<=q-7<=50 else 0
__global__ void prep_kernel(const float* __restrict__ W, const float* __restrict__ PW,
                            const float* __restrict__ C,
                            float* __restrict__ wsmT, u32x4* __restrict__ pwB,
                            float* __restrict__ cpad2) {
    const int lane = threadIdx.x;
    const int wv   = threadIdx.y;
    const int tid  = wv * 64 + lane;
    for (int it = 0; it < 16; ++it) {
        const int r = wv * 16 + it;
        float v = W[r * 64 + lane];
        float m = v;
        #pragma unroll
        for (int off = 32; off >= 1; off >>= 1)
            m = fmaxf(m, __shfl_xor(m, off, 64));
        float e = __expf(v - m);
        float s = e;
        #pragma unroll
        for (int off = 32; off >= 1; off >>= 1)
            s += __shfl_xor(s, off, 64);
        wsmT[lane * 64 + r] = e * rcpf(s);     // [j][i] f32
    }
    for (int s = tid; s < 512; s += 256) {
        const int n2 = s >> 6;
        const int ln = s & 63;
        const int i  = (n2 >> 1) * 16 + (ln & 15);
        const int k0 = (n2 & 1) * 32 + (ln >> 4) * 8;
        u32x4 frag;
        #pragma unroll
        for (int w = 0; w < 4; ++w) {
            const unsigned lo = __half_as_ushort(__float2half_rn(PW[i * 64 + k0 + 2 * w]));
            const unsigned hi = __half_as_ushort(__float2half_rn(PW[i * 64 + k0 + 2 * w + 1]));
            frag[w] = lo | (hi << 16);
        }
        pwB[s] = frag;
    }
    if (tid < 65) {
        const int k = tid - 7;
        cpad2[tid] = (k >= 0 && k <= 50) ? C[k] : 0.f;
    }
}

// ---- fused main: 512 thr / 8 waves, 64-row tile; lane = row, 8 feats/wave;
//      w via wave-uniform s_load (scalar pipe), NOT LDS ----
__global__ __launch_bounds__(512, 4)
void mcao_main(const float* __restrict__ x,
               const float* __restrict__ wsm,
               const u32x4* __restrict__ pwB,
               const float* __restrict__ cpad2,
               const float* __restrict__ pb,
               const float* __restrict__ kap,
               float* __restrict__ out,
               float* __restrict__ memout) {
    // LDS 49696 B -> 2 blocks/CU (grid 512 = exactly 2/CU):
    //   [0, 16416)      xsH f16 [114][72]    (FIR stream + MFMA-A)
    //   [16416, 49696)  tuS f32x2 [64][65]   {t,u}[feat][row]; P2 f32 [64][65] overlays after bar2
    __shared__ __align__(16) char smem[49696];
    __half* xsH = (__half*)smem;
    f32x2*  tuS = (f32x2*)(smem + 16416);
    float*  P2  = (float*)(smem + 16416);

    const int tid  = threadIdx.x;
    const int lane = tid & 63;
    const int wv   = tid >> 6;              // 0..7

    // XCD-aware bijective swizzle: 512 blocks -> 64 consecutive tiles per XCD
    const int sw = ((int)blockIdx.x & 7) * 64 + ((int)blockIdx.x >> 3);
    const int b  = sw >> 7;                 // 0..3
    const int t0 = (sw & 127) * TILE;
    const float* xb = x + (size_t)b * TT * FF;

    // ---- stage xsH (f16) + t/u planes inline (f32 source) ----
    for (int i4 = tid; i4 < ROWS * 16; i4 += 512) {
        const int s = i4 >> 4, f4 = i4 & 15, t = t0 - HALO + s;
        f32x4 v = {0.f, 0.f, 0.f, 0.f};
        if (t >= 0) v = *(const f32x4*)(xb + (size_t)t * 64 + f4 * 4);
        __half hv[4];
        #pragma unroll
        for (int q = 0; q < 4; ++q) hv[q] = __float2half_rn(v[q]);
        *(u32x2*)(&xsH[s * XSTR + f4 * 4]) = *(u32x2*)hv;
        if (s >= HALO) {
            const int row = s - HALO;
            #pragma unroll
            for (int q = 0; q < 4; ++q) {
                f32x2 e;
                e.x = fmaf(-2.f, rcpf(__expf(2.f * v[q]) + 1.f), 1.f);  // tanh
                e.y = __expf(-fabsf(v[q]));                             // e^-|x|
                tuS[(f4 * 4 + q) * 65 + row] = e;
            }
        }
    }
    __syncthreads();                                    // bar1

    // ---- proj via MFMA: wave -> 2 C-tiles (mt = wv>>1, nt = (wv&1)*2 + tb) ----
    const int mt = wv >> 1;
    const int marow = HALO + mt * 16 + (lane & 15);
    const int kcol  = (lane >> 4) * 8;
    f32x4 cfr[2] = {{0.f,0.f,0.f,0.f}, {0.f,0.f,0.f,0.f}};
    #pragma unroll
    for (int tb = 0; tb < 2; ++tb) {
        const int nt = (wv & 1) * 2 + tb;
        #pragma unroll
        for (int kt = 0; kt < 2; ++kt) {
            const f16x8 afr = *(const f16x8*)(&xsH[marow * XSTR + kt * 32 + kcol]);
            const f16x8 bfr = __builtin_bit_cast(f16x8, pwB[(nt * 2 + kt) * 64 + lane]);
            cfr[tb] = __builtin_amdgcn_mfma_f32_16x16x32_f16(afr, bfr, cfr[tb], 0, 0, 0);
        }
    }

    // ---- megaloop setup: lane = row r; wave's 8 feats ib..ib+7 (wave-uniform) ----
    const int r    = lane;
    const int ib_u = __builtin_amdgcn_readfirstlane(wv * 8);   // SGPR
    const float* wbase = wsm + ib_u;                           // uniform pointer
    f32x2 tiP[4], uiP[4];
    #pragma unroll
    for (int q = 0; q < 8; ++q) {
        const f32x2 e = tuS[(ib_u + q) * 65 + r];
        tiP[q >> 1][q & 1] = e.x;
        uiP[q >> 1][q & 1] = e.y;
    }

    float macc[8] = {0,0,0,0,0,0,0,0};
    f32x2 cac[4] = {{0,0},{0,0},{0,0},{0,0}};
    const f32x2 one2 = {1.f, 1.f};
    const int firrow = 8 * wv;

    // ---- megaloop m = 0..63: coupling all m (w via s_load); FIR for m < 58 ----
    #pragma unroll
    for (int m = 0; m < 64; ++m) {
        const f32x2 e = tuS[m * 65 + r];                 // b64, 2-way free
        const f32x4 wA = *(const f32x4*)(wbase + m * 64);     // uniform -> s_load
        const f32x4 wB = *(const f32x4*)(wbase + m * 64 + 4); // uniform -> s_load
        if (m < 58) {
            const float xv = __half2float(xsH[(firrow + m) * XSTR + lane]);
            #pragma unroll
            for (int r2 = 0; r2 < 8; ++r2)
                macc[r2] = fmaf(cpad2[r2 + 57 - m], xv, macc[r2]);  // SGPR coeff
        }
        const f32x2 tjj = {e.x, e.x}, ujj = {e.y, e.y};
        #pragma unroll
        for (int g = 0; g < 4; ++g) {
            const f32x2 d1  = __builtin_elementwise_fma(-tiP[g], tjj, one2);
            const f32x2 d2  = __builtin_elementwise_fma( uiP[g], ujj, one2);
            const f32x2 den = d1 * d2;
            f32x2 rr; rr.x = rcpf(den.x); rr.y = rcpf(den.y);
            const f32x2 s = (tiP[g] - tjj) * rr;
            f32x2 wg;
            wg.x = (g < 2) ? wA[2 * g] : wB[2 * (g - 2)];
            wg.y = (g < 2) ? wA[2 * g + 1] : wB[2 * (g - 2) + 1];
            cac[g] = __builtin_elementwise_fma(wg, s, cac[g]);   // pk_fma, SGPR-pair w
        }
    }

    // ---- memory-term store ----
    #pragma unroll
    for (int r2 = 0; r2 < 8; ++r2)
        memout[(size_t)(b * TT + t0 + firrow + r2) * 64 + lane] = macc[r2];

    __syncthreads();                                    // bar2 (tuS dead)

    // ---- proj C-frags -> P2 (overlays tuS) ----
    #pragma unroll
    for (int tb = 0; tb < 2; ++tb) {
        const int nt = (wv & 1) * 2 + tb;
        const int ic = nt * 16 + (lane & 15);
        const int rb = mt * 16 + (lane >> 4) * 4;
        #pragma unroll
        for (int reg = 0; reg < 4; ++reg)
            P2[ic * 65 + rb + reg] = cfr[tb][reg];
    }
    __syncthreads();                                    // bar3

    // ---- epilogue RMW: P2 <- 0.4c + 0.3(proj+pb)ksum ----
    const float kappa = kap[0];
    const float ksum  = (1.f - __expf(-kappa * (float)(t0 + r + 1))) *
                        rcpf(1.f - __expf(-kappa));
    #pragma unroll
    for (int q = 0; q < 8; ++q) {
        const float cv  = (q & 1) ? cac[q >> 1].y : cac[q >> 1].x;
        const int   idx = (ib_u + q) * 65 + r;
        P2[idx] = fmaf(0.4f, cv, 0.3f * (P2[idx] + pb[ib_u + q]) * ksum);
    }
    __syncthreads();                                    // bar4

    // ---- final store: wave rows 8wv..8wv+7, lane = feature (coalesced) ----
    #pragma unroll
    for (int rr2 = 0; rr2 < 8; ++rr2) {
        const int row = firrow + rr2;
        out[(size_t)(b * TT + t0 + row) * 64 + lane] =
            fmaf(0.3f, macc[rr2], P2[lane * 65 + row]);  // (lane+row)%32 distinct: free
    }
}

extern "C" void kernel_launch(void* const* d_in, const int* in_sizes, int n_in,
                              void* d_out, int out_size, void* d_ws, size_t ws_size,
                              hipStream_t stream) {
    const float* x   = (const float*)d_in[0];
    const float* W   = (const float*)d_in[1];
    const float* PW  = (const float*)d_in[2];
    const float* pb  = (const float*)d_in[3];
    const float* kap = (const float*)d_in[4];
    const float* cf  = (const float*)d_in[5];

    float* out    = (float*)d_out;
    float* memout = out + (size_t)4 * TT * FF;

    float*  wsmT  = (float*)d_ws;                        // 16 KB
    u32x4*  pwB   = (u32x4*)((char*)d_ws + 16384);       //  8 KB
    float*  cpad2 = (float*)((char*)d_ws + 24576);       // 260 B

    hipLaunchKernelGGL(prep_kernel, dim3(1), dim3(64, 4), 0, stream,
                       W, PW, cf, wsmT, pwB, cpad2);
    hipLaunchKernelGGL(mcao_main, dim3(4 * (TT / TILE)), dim3(512), 0, stream,
                       x, wsmT, pwB, cpad2, pb, kap, out, memout);
}